// Round 7
// baseline (570.543 us; speedup 1.0000x reference)
//
#include <hip/hip_runtime.h>
#include <hip/hip_bf16.h>

// MPNN: B=8, N=36, H=64, STEPS=5
// messages[b,j,k] = (1/N^2) * sum_{i,l} edge[b,i,j,k,l] * nodes[b,i,l]
// nodes = GRUCell(messages, nodes) * mask, repeated STEPS times.
//
// Structure: 1 memset + 5 kernels (one per step). Each step kernel:
//   grid = B*N*GG blocks x 64 threads; block (b,j,g) computes the partial
//   einsum over its 3 i's, agent-stores it, then atomically bumps cnt[b,j].
//   The LAST block per (b,j) (old==GG-1) reduces the 12 partials, runs the
//   GRU cell for node (b,j), and writes nodes_out (d_out on the last step).
// Step 1 streams the f32 edge tensor and emits a bf16 copy; steps 2-5 stream
// the bf16 copy (85 MB).

#define BB 8
#define NN 36
#define HH 64
#define GG 12           // i-groups per (b,j)
#define IPG (NN / GG)   // 3
#define NSTEPS 5
#define NBJ (BB * NN)   // 288
#define INVN2 (1.0f / (float)(NN * NN))

__device__ __forceinline__ unsigned bf16rtn(float f) {
    unsigned u = __float_as_uint(f);
    return (u + 0x7FFFu + ((u >> 16) & 1u)) >> 16;
}

__device__ __forceinline__ float agent_load(const float* p) {
    return __hip_atomic_load(p, __ATOMIC_RELAXED, __HIP_MEMORY_SCOPE_AGENT);
}
__device__ __forceinline__ void agent_store(float* p, float v) {
    __hip_atomic_store(p, v, __ATOMIC_RELAXED, __HIP_MEMORY_SCOPE_AGENT);
}

// GRU tail, run by the last-arriving block of each (b,j). Single wave.
__device__ __forceinline__ void gru_tail(
    const float* __restrict__ partial,
    const float* __restrict__ nodes_prev,
    const float* __restrict__ mask,
    const float* __restrict__ w_ih, const float* __restrict__ w_hh,
    const float* __restrict__ b_ih, const float* __restrict__ b_hh,
    float* __restrict__ nodes_out, int bj, int t)
{
    __shared__ float ms[HH];
    __shared__ float hs[HH];

    float m = 0.f;
    #pragma unroll
    for (int g = 0; g < GG; ++g)
        m += agent_load(&partial[((size_t)bj * GG + g) * HH + t]);
    ms[t] = m * INVN2;
    hs[t] = nodes_prev[bj * HH + t];
    __syncthreads();

    float gi0 = b_ih[t], gi1 = b_ih[HH + t], gi2 = b_ih[2 * HH + t];
    float gh0 = b_hh[t], gh1 = b_hh[HH + t], gh2 = b_hh[2 * HH + t];

    const float4* __restrict__ wi0 = (const float4*)(w_ih + (0 * HH + t) * HH);
    const float4* __restrict__ wi1 = (const float4*)(w_ih + (1 * HH + t) * HH);
    const float4* __restrict__ wi2 = (const float4*)(w_ih + (2 * HH + t) * HH);
    const float4* __restrict__ wh0 = (const float4*)(w_hh + (0 * HH + t) * HH);
    const float4* __restrict__ wh1 = (const float4*)(w_hh + (1 * HH + t) * HH);
    const float4* __restrict__ wh2 = (const float4*)(w_hh + (2 * HH + t) * HH);

    #pragma unroll
    for (int k4 = 0; k4 < HH / 4; ++k4) {
        const float4 mv = *(const float4*)&ms[k4 * 4];
        const float4 hv = *(const float4*)&hs[k4 * 4];
        float4 a;
        a = wi0[k4]; gi0 += a.x * mv.x + a.y * mv.y + a.z * mv.z + a.w * mv.w;
        a = wi1[k4]; gi1 += a.x * mv.x + a.y * mv.y + a.z * mv.z + a.w * mv.w;
        a = wi2[k4]; gi2 += a.x * mv.x + a.y * mv.y + a.z * mv.z + a.w * mv.w;
        a = wh0[k4]; gh0 += a.x * hv.x + a.y * hv.y + a.z * hv.z + a.w * hv.w;
        a = wh1[k4]; gh1 += a.x * hv.x + a.y * hv.y + a.z * hv.z + a.w * hv.w;
        a = wh2[k4]; gh2 += a.x * hv.x + a.y * hv.y + a.z * hv.z + a.w * hv.w;
    }
    const float r = 1.f / (1.f + expf(-(gi0 + gh0)));
    const float z = 1.f / (1.f + expf(-(gi1 + gh1)));
    const float n = tanhf(gi2 + r * gh2);
    const float outv = ((1.f - z) * n + z * hs[t]) * mask[bj];
    nodes_out[bj * HH + t] = outv;
}

// ---------------------------------------------------------------------------
// Step 1: einsum on f32 edge + emit bf16 copy + atomic-tailed GRU.
// ---------------------------------------------------------------------------
__global__ __launch_bounds__(64) void step_f32(
    const float* __restrict__ edge,
    const float* __restrict__ nodes,
    uint2* __restrict__ ebf,
    float* __restrict__ partial,
    int* __restrict__ cnt,
    const float* __restrict__ mask,
    const float* __restrict__ w_ih, const float* __restrict__ w_hh,
    const float* __restrict__ b_ih, const float* __restrict__ b_hh,
    float* __restrict__ nodes_out)
{
    const int lane = threadIdx.x;
    const int bid  = blockIdx.x;
    const int g  = bid % GG;
    const int bj = bid / GG;          // b*NN + j
    const int j  = bj % NN;
    const int b  = bj / NN;

    const int l4 = lane & 15;

    float acc[16];
    #pragma unroll
    for (int it = 0; it < 16; ++it) acc[it] = 0.f;

    #pragma unroll
    for (int ii = 0; ii < IPG; ++ii) {
        const int i = g * IPG + ii;
        const float4 v = *(const float4*)(nodes + (b * NN + i) * HH + l4 * 4);
        const size_t blkElem = (size_t)((b * NN + i) * NN + j) * (HH * HH);
        const float4* __restrict__ Wb = (const float4*)(edge + blkElem);
        uint2* __restrict__ Eb = ebf + (blkElem >> 2);
        #pragma unroll
        for (int it = 0; it < 16; ++it) {
            const float4 w = Wb[it * 64 + lane];
            acc[it] = fmaf(w.x, v.x, acc[it]);
            acc[it] = fmaf(w.y, v.y, acc[it]);
            acc[it] = fmaf(w.z, v.z, acc[it]);
            acc[it] = fmaf(w.w, v.w, acc[it]);
            uint2 pk;
            pk.x = bf16rtn(w.x) | (bf16rtn(w.y) << 16);
            pk.y = bf16rtn(w.z) | (bf16rtn(w.w) << 16);
            Eb[it * 64 + lane] = pk;
        }
    }

    #pragma unroll
    for (int m = 1; m < 16; m <<= 1) {
        #pragma unroll
        for (int it = 0; it < 16; ++it)
            acc[it] += __shfl_xor(acc[it], m, 64);
    }

    const int p  = lane & 15;
    const int gq = lane >> 4;
    float outv = acc[0];
    #pragma unroll
    for (int t = 1; t < 16; ++t) outv = (p == t) ? acc[t] : outv;

    agent_store(&partial[(size_t)bid * HH + (4 * p + gq)], outv);

    int old = 0;
    if (lane == 0)
        old = __hip_atomic_fetch_add(&cnt[bj], 1, __ATOMIC_ACQ_REL,
                                     __HIP_MEMORY_SCOPE_AGENT);
    old = __shfl(old, 0, 64);
    if (old == GG - 1)
        gru_tail(partial, nodes, mask, w_ih, w_hh, b_ih, b_hh,
                 nodes_out, bj, lane);
}

// ---------------------------------------------------------------------------
// Steps 2..5: einsum on bf16 edge copy + atomic-tailed GRU.
// ---------------------------------------------------------------------------
__global__ __launch_bounds__(64) void step_bf16(
    const uint4* __restrict__ ebf,
    const float* __restrict__ nodes,
    float* __restrict__ partial,
    int* __restrict__ cnt,
    const float* __restrict__ mask,
    const float* __restrict__ w_ih, const float* __restrict__ w_hh,
    const float* __restrict__ b_ih, const float* __restrict__ b_hh,
    float* __restrict__ nodes_out)
{
    const int lane = threadIdx.x;
    const int bid  = blockIdx.x;
    const int g  = bid % GG;
    const int bj = bid / GG;
    const int j  = bj % NN;
    const int b  = bj / NN;

    const int l8 = lane & 7;

    float acc[8];
    #pragma unroll
    for (int it = 0; it < 8; ++it) acc[it] = 0.f;

    #pragma unroll
    for (int ii = 0; ii < IPG; ++ii) {
        const int i = g * IPG + ii;
        const float* np_ = nodes + (b * NN + i) * HH + l8 * 8;
        const float4 v0 = *(const float4*)(np_);
        const float4 v1 = *(const float4*)(np_ + 4);
        const size_t blkElem = (size_t)((b * NN + i) * NN + j) * (HH * HH);
        const uint4* __restrict__ Wb = ebf + (blkElem >> 3);
        #pragma unroll
        for (int it = 0; it < 8; ++it) {
            const uint4 w = Wb[it * 64 + lane];
            acc[it] = fmaf(__uint_as_float(w.x << 16),          v0.x, acc[it]);
            acc[it] = fmaf(__uint_as_float(w.x & 0xffff0000u),  v0.y, acc[it]);
            acc[it] = fmaf(__uint_as_float(w.y << 16),          v0.z, acc[it]);
            acc[it] = fmaf(__uint_as_float(w.y & 0xffff0000u),  v0.w, acc[it]);
            acc[it] = fmaf(__uint_as_float(w.z << 16),          v1.x, acc[it]);
            acc[it] = fmaf(__uint_as_float(w.z & 0xffff0000u),  v1.y, acc[it]);
            acc[it] = fmaf(__uint_as_float(w.w << 16),          v1.z, acc[it]);
            acc[it] = fmaf(__uint_as_float(w.w & 0xffff0000u),  v1.w, acc[it]);
        }
    }

    #pragma unroll
    for (int m = 1; m < 8; m <<= 1) {
        #pragma unroll
        for (int it = 0; it < 8; ++it)
            acc[it] += __shfl_xor(acc[it], m, 64);
    }

    const int p  = lane & 7;
    const int gq = lane >> 3;
    float outv = acc[0];
    #pragma unroll
    for (int tt = 1; tt < 8; ++tt) outv = (p == tt) ? acc[tt] : outv;

    agent_store(&partial[(size_t)bid * HH + (8 * p + gq)], outv);

    int old = 0;
    if (lane == 0)
        old = __hip_atomic_fetch_add(&cnt[bj], 1, __ATOMIC_ACQ_REL,
                                     __HIP_MEMORY_SCOPE_AGENT);
    old = __shfl(old, 0, 64);
    if (old == GG - 1)
        gru_tail(partial, nodes, mask, w_ih, w_hh, b_ih, b_hh,
                 nodes_out, bj, lane);
}

extern "C" void kernel_launch(void* const* d_in, const int* in_sizes, int n_in,
                              void* d_out, int out_size, void* d_ws, size_t ws_size,
                              hipStream_t stream) {
    const float* edge   = (const float*)d_in[0];
    const float* nodes0 = (const float*)d_in[1];
    const float* mask   = (const float*)d_in[2];
    const float* w_ih   = (const float*)d_in[3];
    const float* w_hh   = (const float*)d_in[4];
    const float* b_ih   = (const float*)d_in[5];
    const float* b_hh   = (const float*)d_in[6];
    float* out = (float*)d_out;

    float* ws = (float*)d_ws;
    const int nodes_elems   = BB * NN * HH;        // 18432
    const int partial_elems = NBJ * GG * HH;       // 221184
    float* nodesA  = ws;
    float* nodesB  = ws + nodes_elems;
    float* partial = ws + 2 * nodes_elems;
    int*   cnt     = (int*)(partial + partial_elems);      // NSTEPS*NBJ ints
    float* ebf_f   = (float*)(cnt + NSTEPS * NBJ);         // bf16 copy ~85 MB
    uint2* ebf2 = (uint2*)ebf_f;
    const uint4* ebf4 = (const uint4*)ebf_f;

    const int grid_e = NBJ * GG;   // 3456

    hipMemsetAsync(cnt, 0, NSTEPS * NBJ * sizeof(int), stream);

    // step 1: nodes1 = GRU(msg(edge_f32, nodes0), nodes0); emit bf16 copy
    step_f32<<<grid_e, 64, 0, stream>>>(edge, nodes0, ebf2, partial,
                                        cnt + 0 * NBJ, mask,
                                        w_ih, w_hh, b_ih, b_hh, nodesA);
    // steps 2..5 on the bf16 copy
    step_bf16<<<grid_e, 64, 0, stream>>>(ebf4, nodesA, partial,
                                         cnt + 1 * NBJ, mask,
                                         w_ih, w_hh, b_ih, b_hh, nodesB);
    step_bf16<<<grid_e, 64, 0, stream>>>(ebf4, nodesB, partial,
                                         cnt + 2 * NBJ, mask,
                                         w_ih, w_hh, b_ih, b_hh, nodesA);
    step_bf16<<<grid_e, 64, 0, stream>>>(ebf4, nodesA, partial,
                                         cnt + 3 * NBJ, mask,
                                         w_ih, w_hh, b_ih, b_hh, nodesB);
    step_bf16<<<grid_e, 64, 0, stream>>>(ebf4, nodesB, partial,
                                         cnt + 4 * NBJ, mask,
                                         w_ih, w_hh, b_ih, b_hh, out);
}

// Round 8
// 143.046 us; speedup vs baseline: 3.9885x; 3.9885x over previous
//
#include <hip/hip_runtime.h>
#include <hip/hip_bf16.h>

// MPNN: B=8, N=36, H=64, STEPS=5
// messages[b,j,k] = (1/N^2) * sum_{i,l} edge[b,i,j,k,l] * nodes[b,i,l]
// nodes = GRUCell(messages, nodes) * mask, repeated STEPS times.
//
// Structure: 6 kernels, one per step (step1 also emits a bf16 edge copy).
// Each block owns ONE (b,j) node: 256 threads = 4 waves; wave w streams
// i in {9w..9w+8}; per-wave einsum partial -> LDS; __syncthreads; wave 0
// reduces the 4 partials and runs the GRU cell inline. No cross-block
// communication, no redundant work, launch count 10 -> 6.

#define BB 8
#define NN 36
#define HH 64
#define WAVES 4
#define IPW (NN / WAVES)   // 9 i's per wave
#define NBJ (BB * NN)      // 288 blocks
#define INVN2 (1.0f / (float)(NN * NN))

__device__ __forceinline__ unsigned bf16rtn(float f) {
    unsigned u = __float_as_uint(f);
    return (u + 0x7FFFu + ((u >> 16) & 1u)) >> 16;
}

// GRU cell for one node; lane t computes output dim t from LDS-staged
// message (ms) and hidden (hs) vectors. Rows t, t+64, t+128 of w_ih/w_hh.
__device__ __forceinline__ float gru_lane(
    const float* __restrict__ ms, const float* __restrict__ hs, int t,
    const float* __restrict__ w_ih, const float* __restrict__ w_hh,
    const float* __restrict__ b_ih, const float* __restrict__ b_hh)
{
    float gi0 = b_ih[t], gi1 = b_ih[HH + t], gi2 = b_ih[2 * HH + t];
    float gh0 = b_hh[t], gh1 = b_hh[HH + t], gh2 = b_hh[2 * HH + t];

    const float4* __restrict__ wi0 = (const float4*)(w_ih + (0 * HH + t) * HH);
    const float4* __restrict__ wi1 = (const float4*)(w_ih + (1 * HH + t) * HH);
    const float4* __restrict__ wi2 = (const float4*)(w_ih + (2 * HH + t) * HH);
    const float4* __restrict__ wh0 = (const float4*)(w_hh + (0 * HH + t) * HH);
    const float4* __restrict__ wh1 = (const float4*)(w_hh + (1 * HH + t) * HH);
    const float4* __restrict__ wh2 = (const float4*)(w_hh + (2 * HH + t) * HH);

    #pragma unroll
    for (int k4 = 0; k4 < HH / 4; ++k4) {
        const float4 mv = *(const float4*)&ms[k4 * 4];
        const float4 hv = *(const float4*)&hs[k4 * 4];
        float4 a;
        a = wi0[k4]; gi0 += a.x * mv.x + a.y * mv.y + a.z * mv.z + a.w * mv.w;
        a = wi1[k4]; gi1 += a.x * mv.x + a.y * mv.y + a.z * mv.z + a.w * mv.w;
        a = wi2[k4]; gi2 += a.x * mv.x + a.y * mv.y + a.z * mv.z + a.w * mv.w;
        a = wh0[k4]; gh0 += a.x * hv.x + a.y * hv.y + a.z * hv.z + a.w * hv.w;
        a = wh1[k4]; gh1 += a.x * hv.x + a.y * hv.y + a.z * hv.z + a.w * hv.w;
        a = wh2[k4]; gh2 += a.x * hv.x + a.y * hv.y + a.z * hv.z + a.w * hv.w;
    }
    const float r = 1.f / (1.f + expf(-(gi0 + gh0)));
    const float z = 1.f / (1.f + expf(-(gi1 + gh1)));
    const float n = tanhf(gi2 + r * gh2);
    return (1.f - z) * n + z * hs[t];
}

// ---------------------------------------------------------------------------
// Step 1: einsum on f32 edge + emit bf16 copy + in-block GRU.
// grid = 288 blocks x 256 threads. Block bj; wave w streams i = 9w..9w+8.
// Per i: lane reads float4 chunk it*64+lane (coalesced 1KB/instr);
// k = 4*it + lane/16, l4 = lane&15. acc[16] static; 4-stage butterfly over
// low 4 lane bits; lane (p,gq) holds k = 4p+gq -> LDS part[w][k].
// ---------------------------------------------------------------------------
__global__ __launch_bounds__(256, 2) void step1_f32(
    const float* __restrict__ edge,
    const float* __restrict__ nodes_in,
    uint2* __restrict__ ebf,
    const float* __restrict__ mask,
    const float* __restrict__ w_ih, const float* __restrict__ w_hh,
    const float* __restrict__ b_ih, const float* __restrict__ b_hh,
    float* __restrict__ nodes_out)
{
    const int tid  = threadIdx.x;
    const int lane = tid & 63;
    const int wv   = tid >> 6;
    const int bj = blockIdx.x;
    const int j  = bj % NN;
    const int b  = bj / NN;

    __shared__ float part[WAVES][HH];
    __shared__ float ms[HH];
    __shared__ float hs[HH];

    const int l4 = lane & 15;

    float acc[16];
    #pragma unroll
    for (int it = 0; it < 16; ++it) acc[it] = 0.f;

    for (int ii = 0; ii < IPW; ++ii) {
        const int i = wv * IPW + ii;
        const float4 v = *(const float4*)(nodes_in + (b * NN + i) * HH + l4 * 4);
        const size_t blkElem = (size_t)((b * NN + i) * NN + j) * (HH * HH);
        const float4* __restrict__ Wb = (const float4*)(edge + blkElem);
        uint2* __restrict__ Eb = ebf + (blkElem >> 2);
        #pragma unroll
        for (int it = 0; it < 16; ++it) {
            const float4 w = Wb[it * 64 + lane];
            acc[it] = fmaf(w.x, v.x, acc[it]);
            acc[it] = fmaf(w.y, v.y, acc[it]);
            acc[it] = fmaf(w.z, v.z, acc[it]);
            acc[it] = fmaf(w.w, v.w, acc[it]);
            uint2 pk;
            pk.x = bf16rtn(w.x) | (bf16rtn(w.y) << 16);
            pk.y = bf16rtn(w.z) | (bf16rtn(w.w) << 16);
            Eb[it * 64 + lane] = pk;
        }
    }

    #pragma unroll
    for (int m = 1; m < 16; m <<= 1) {
        #pragma unroll
        for (int it = 0; it < 16; ++it)
            acc[it] += __shfl_xor(acc[it], m, 64);
    }

    const int p  = lane & 15;
    const int gq = lane >> 4;
    float outv = acc[0];
    #pragma unroll
    for (int t = 1; t < 16; ++t) outv = (p == t) ? acc[t] : outv;
    part[wv][4 * p + gq] = outv;

    __syncthreads();

    if (tid < HH) {
        const float m = part[0][tid] + part[1][tid] + part[2][tid] + part[3][tid];
        ms[tid] = m * INVN2;
        hs[tid] = nodes_in[bj * HH + tid];
    }
    __syncthreads();

    if (tid < HH) {
        const float o = gru_lane(ms, hs, tid, w_ih, w_hh, b_ih, b_hh);
        nodes_out[bj * HH + tid] = o * mask[bj];
    }
}

// ---------------------------------------------------------------------------
// Steps 2..5: einsum on bf16 edge copy + in-block GRU.
// Per i: 8 uint4 (16B) chunks; k = 8*it + lane/8, l8 = lane&7. acc[8];
// 3-stage butterfly; lane (p,gq) holds k = 8p+gq -> LDS part[w][k].
// ---------------------------------------------------------------------------
__global__ __launch_bounds__(256, 2) void step_bf16(
    const uint4* __restrict__ ebf,
    const float* __restrict__ nodes_in,
    const float* __restrict__ mask,
    const float* __restrict__ w_ih, const float* __restrict__ w_hh,
    const float* __restrict__ b_ih, const float* __restrict__ b_hh,
    float* __restrict__ nodes_out)
{
    const int tid  = threadIdx.x;
    const int lane = tid & 63;
    const int wv   = tid >> 6;
    const int bj = blockIdx.x;
    const int j  = bj % NN;
    const int b  = bj / NN;

    __shared__ float part[WAVES][HH];
    __shared__ float ms[HH];
    __shared__ float hs[HH];

    const int l8 = lane & 7;

    float acc[8];
    #pragma unroll
    for (int it = 0; it < 8; ++it) acc[it] = 0.f;

    for (int ii = 0; ii < IPW; ++ii) {
        const int i = wv * IPW + ii;
        const float* np_ = nodes_in + (b * NN + i) * HH + l8 * 8;
        const float4 v0 = *(const float4*)(np_);
        const float4 v1 = *(const float4*)(np_ + 4);
        const size_t blkElem = (size_t)((b * NN + i) * NN + j) * (HH * HH);
        const uint4* __restrict__ Wb = ebf + (blkElem >> 3);
        #pragma unroll
        for (int it = 0; it < 8; ++it) {
            const uint4 w = Wb[it * 64 + lane];
            acc[it] = fmaf(__uint_as_float(w.x << 16),          v0.x, acc[it]);
            acc[it] = fmaf(__uint_as_float(w.x & 0xffff0000u),  v0.y, acc[it]);
            acc[it] = fmaf(__uint_as_float(w.y << 16),          v0.z, acc[it]);
            acc[it] = fmaf(__uint_as_float(w.y & 0xffff0000u),  v0.w, acc[it]);
            acc[it] = fmaf(__uint_as_float(w.z << 16),          v1.x, acc[it]);
            acc[it] = fmaf(__uint_as_float(w.z & 0xffff0000u),  v1.y, acc[it]);
            acc[it] = fmaf(__uint_as_float(w.w << 16),          v1.z, acc[it]);
            acc[it] = fmaf(__uint_as_float(w.w & 0xffff0000u),  v1.w, acc[it]);
        }
    }

    #pragma unroll
    for (int m = 1; m < 8; m <<= 1) {
        #pragma unroll
        for (int it = 0; it < 8; ++it)
            acc[it] += __shfl_xor(acc[it], m, 64);
    }

    const int p  = lane & 7;
    const int gq = lane >> 3;
    float outv = acc[0];
    #pragma unroll
    for (int tt = 1; tt < 8; ++tt) outv = (p == tt) ? acc[tt] : outv;
    part[wv][8 * p + gq] = outv;

    __syncthreads();

    if (tid < HH) {
        const float m = part[0][tid] + part[1][tid] + part[2][tid] + part[3][tid];
        ms[tid] = m * INVN2;
        hs[tid] = nodes_in[bj * HH + tid];
    }
    __syncthreads();

    if (tid < HH) {
        const float o = gru_lane(ms, hs, tid, w_ih, w_hh, b_ih, b_hh);
        nodes_out[bj * HH + tid] = o * mask[bj];
    }
}

extern "C" void kernel_launch(void* const* d_in, const int* in_sizes, int n_in,
                              void* d_out, int out_size, void* d_ws, size_t ws_size,
                              hipStream_t stream) {
    const float* edge   = (const float*)d_in[0];
    const float* nodes0 = (const float*)d_in[1];
    const float* mask   = (const float*)d_in[2];
    const float* w_ih   = (const float*)d_in[3];
    const float* w_hh   = (const float*)d_in[4];
    const float* b_ih   = (const float*)d_in[5];
    const float* b_hh   = (const float*)d_in[6];
    float* out = (float*)d_out;

    float* ws = (float*)d_ws;
    const int nodes_elems = BB * NN * HH;          // 18432
    float* nodesA = ws;
    float* nodesB = ws + nodes_elems;
    float* ebf_f  = ws + 2 * nodes_elems;          // bf16 edge copy ~85 MB
    uint2* ebf2 = (uint2*)ebf_f;
    const uint4* ebf4 = (const uint4*)ebf_f;

    // step 1: nodes1 = GRU(msg(edge_f32, nodes0), nodes0); emit bf16 copy
    step1_f32<<<NBJ, 256, 0, stream>>>(edge, nodes0, ebf2, mask,
                                       w_ih, w_hh, b_ih, b_hh, nodesA);
    // steps 2..5 on the bf16 copy
    step_bf16<<<NBJ, 256, 0, stream>>>(ebf4, nodesA, mask,
                                       w_ih, w_hh, b_ih, b_hh, nodesB);
    step_bf16<<<NBJ, 256, 0, stream>>>(ebf4, nodesB, mask,
                                       w_ih, w_hh, b_ih, b_hh, nodesA);
    step_bf16<<<NBJ, 256, 0, stream>>>(ebf4, nodesA, mask,
                                       w_ih, w_hh, b_ih, b_hh, nodesB);
    step_bf16<<<NBJ, 256, 0, stream>>>(ebf4, nodesB, mask,
                                       w_ih, w_hh, b_ih, b_hh, out);
}